// Round 8
// baseline (247.401 us; speedup 1.0000x reference)
//
#include <hip/hip_runtime.h>
#include <hip/hip_bf16.h>
#include <cstdint>
#include <cstddef>

#define NP 20000
#define NA 10000
#define NEDGE 100000
#define NEG_INF (-__builtin_huge_valf())
#define INV_SQRT_DK 0.17677669529663687f

typedef __bf16 bf16_t;
typedef __attribute__((ext_vector_type(8))) short s16x8;
typedef __attribute__((ext_vector_type(4))) float f32x4;
typedef __attribute__((ext_vector_type(4))) __bf16 bf16x4;
typedef __attribute__((ext_vector_type(8))) __bf16 bf16x8v;

union B16 { uint4 u; s16x8 s; bf16x8v b; };

// ---------- fill ----------
__global__ __launch_bounds__(256) void fill_u32(unsigned* __restrict__ p, unsigned v, int n) {
    int i = blockIdx.x * 256 + threadIdx.x;
    if (i < n) p[i] = v;
}

// ---------- CSR build (3 etypes per launch) ----------
__global__ __launch_bounds__(256) void count3(
    const int* __restrict__ d0, const int* __restrict__ d1, const int* __restrict__ d2,
    int* __restrict__ c0, int* __restrict__ c1, int* __restrict__ c2, int E)
{
    int e = blockIdx.x * 256 + threadIdx.x;
    if (e >= E) return;
    const int* d; int* c;
    switch (blockIdx.y) { case 0: d = d0; c = c0; break; case 1: d = d1; c = c1; break; default: d = d2; c = c2; }
    atomicAdd(c + d[e], 1);
}

__global__ __launch_bounds__(256) void scan3(
    const int* __restrict__ c0, const int* __restrict__ c1, const int* __restrict__ c2,
    int* __restrict__ r0, int* __restrict__ r1, int* __restrict__ r2)
{
    const int* cnt; int* rp; int n;
    switch (blockIdx.x) { case 0: cnt = c0; rp = r0; n = NP; break;
                          case 1: cnt = c1; rp = r1; n = NP; break;
                          default: cnt = c2; rp = r2; n = NA; }
    __shared__ int sums[256];
    __shared__ int offs[257];
    const int t = threadIdx.x;
    const int chunk = (n + 255) / 256;
    const int lo = min(t * chunk, n), hi = min(lo + chunk, n);
    int s = 0;
    for (int i = lo; i < hi; ++i) s += cnt[i];
    sums[t] = s;
    __syncthreads();
    if (t == 0) {
        int a = 0;
        for (int i = 0; i < 256; ++i) { offs[i] = a; a += sums[i]; }
        rp[n] = a;
    }
    __syncthreads();
    int a = offs[t];
    for (int i = lo; i < hi; ++i) { rp[i] = a; a += cnt[i]; }
}

__global__ __launch_bounds__(256) void scatter3(
    const int* __restrict__ s0, const int* __restrict__ d0,
    const int* __restrict__ s1, const int* __restrict__ d1,
    const int* __restrict__ s2, const int* __restrict__ d2,
    const int* __restrict__ r0, const int* __restrict__ r1, const int* __restrict__ r2,
    int* __restrict__ run0, int* __restrict__ run1, int* __restrict__ run2,
    int* __restrict__ sr0, int* __restrict__ sr1, int* __restrict__ sr2, int E)
{
    int e = blockIdx.x * 256 + threadIdx.x;
    if (e >= E) return;
    const int *src, *dst, *rp; int *run, *srs;
    switch (blockIdx.y) {
        case 0: src = s0; dst = d0; rp = r0; run = run0; srs = sr0; break;
        case 1: src = s1; dst = d1; rp = r1; run = run1; srs = sr1; break;
        default: src = s2; dst = d2; rp = r2; run = run2; srs = sr2;
    }
    int d = dst[e];
    int pos = atomicAdd(run + d, 1);
    srs[rp[d] + pos] = src[e];
}

// ---------- weight prep: 6 fused (proj x rel) + 4 plain transposes, all bf16 transposed ----------
__global__ __launch_bounds__(256) void prep_weights(
    const float* __restrict__ k_w, const float* __restrict__ k_b,
    const float* __restrict__ v_w, const float* __restrict__ v_b,
    const float* __restrict__ q_w, const float* __restrict__ a_w,
    const float* __restrict__ rel_att, const float* __restrict__ rel_msg,
    bf16_t* __restrict__ WT_hp, float* __restrict__ Bhp,
    bf16_t* __restrict__ WT_ha, float* __restrict__ Bha,
    bf16_t* __restrict__ WT_q0, bf16_t* __restrict__ WT_q1,
    bf16_t* __restrict__ WT_a0, bf16_t* __restrict__ WT_a1)
{
    const int y = blockIdx.y;
    const int c = blockIdx.x;
    const int t = threadIdx.x;
    if (y < 6) {
        const float *W, *b, *R; bf16_t* WT; float* bias;
        switch (y) {
            case 0: W = k_w;         b = k_b;       R = rel_att + 8192;  WT = WT_hp;          bias = Bhp;       break;
            case 1: W = v_w;         b = v_b;       R = rel_msg + 8192;  WT = WT_hp + 65536;  bias = Bhp + 256; break;
            case 2: W = k_w;         b = k_b;       R = rel_att + 16384; WT = WT_hp + 131072; bias = Bhp + 512; break;
            case 3: W = v_w;         b = v_b;       R = rel_msg + 16384; WT = WT_hp + 196608; bias = Bhp + 768; break;
            case 4: W = k_w + 65536; b = k_b + 256; R = rel_att;         WT = WT_ha;          bias = Bha;       break;
            default:W = v_w + 65536; b = v_b + 256; R = rel_msg;         WT = WT_ha + 65536;  bias = Bha + 256;
        }
        __shared__ float rs[32];
        const int h = c >> 5, e = c & 31;
        if (t < 32) rs[t] = R[(h * 32 + t) * 32 + e];
        __syncthreads();
        float s = 0.f;
#pragma unroll
        for (int d = 0; d < 32; ++d) s += W[t * 256 + h * 32 + d] * rs[d];
        WT[c * 256 + t] = (bf16_t)s;
        if (t == 0) {
            float sb = 0.f;
#pragma unroll
            for (int d = 0; d < 32; ++d) sb += b[h * 32 + d] * rs[d];
            bias[c] = sb;
        }
    } else {
        const float* W; bf16_t* WT;
        switch (y) { case 6: W = q_w; WT = WT_q0; break;
                     case 7: W = q_w + 65536; WT = WT_q1; break;
                     case 8: W = a_w; WT = WT_a0; break;
                     default: W = a_w + 65536; WT = WT_a1; }
        WT[c * 256 + t] = (bf16_t)W[t * 256 + c];
    }
}

// ---------- segmented bf16 MFMA GEMM: single-buffer LDS + register prefetch ----------
// Y[M,ldY] = X[M,256] @ WT^T + bias per segment. WT row-major bf16 [N][256].
// Col-fastest block mapping (X-tile reuse in L2/L3); LDS-staged coalesced bf16 epilogue.
struct GSeg {
    const void* X; const bf16_t* WT; const float* bias; void* Y;
    int M, ncb, ldY, blk0;
};
struct GSegs { GSeg s[4]; int n; };

template<int IN_BF16, int OUT_BF16>
__global__ __launch_bounds__(256) void gemm_seg(GSegs segs)
{
    int si = 0;
#pragma unroll
    for (int i = 1; i < 4; ++i)
        if (i < segs.n && (int)blockIdx.x >= segs.s[i].blk0) si = i;
    const GSeg g = segs.s[si];
    const int lid = blockIdx.x - g.blk0;
    const int by = lid % g.ncb;      // col-fastest: consecutive blocks share the X row-tile
    const int bx = lid / g.ncb;
    const int row0 = bx * 128, col0 = by * 128;
    const int M = g.M, ldY = g.ldY;
    const bf16_t* __restrict__ WT = g.WT;

    __shared__ uint4 AB[2][512];                       // [A/B][row*4+slot], XOR-swizzled, 16 KB
    __shared__ ushort epi[4][16][OUT_BF16 ? 72 : 2];   // per-wave epilogue transpose staging
    const int t = threadIdx.x;
    const int w = t >> 6, l = t & 63;
    const int wm = w >> 1, wn = w & 1;
    const int lr = l & 15, ks4 = l >> 4;
    const int r0t = t >> 2, st = t & 3;

    float4 pa[2][2];
    uint4 pab[2], pb[2];

    auto LOADK = [&](int k0) {
#pragma unroll
        for (int j = 0; j < 2; ++j) {
            const int gr = row0 + r0t + j * 64;
            if (IN_BF16) {
                if (gr < M) pab[j] = *(const uint4*)((const bf16_t*)g.X + (size_t)gr * 256 + k0 + st * 8);
                else pab[j] = make_uint4(0, 0, 0, 0);
            } else {
                if (gr < M) {
                    const float* xp = (const float*)g.X + (size_t)gr * 256 + k0 + st * 8;
                    pa[j][0] = *(const float4*)xp;
                    pa[j][1] = *(const float4*)(xp + 4);
                } else {
                    pa[j][0] = make_float4(0.f, 0.f, 0.f, 0.f);
                    pa[j][1] = make_float4(0.f, 0.f, 0.f, 0.f);
                }
            }
            pb[j] = *(const uint4*)(WT + (size_t)(col0 + r0t + j * 64) * 256 + k0 + st * 8);
        }
    };
    auto WRITE = [&]() {
#pragma unroll
        for (int j = 0; j < 2; ++j) {
            const int r = r0t + j * 64;
            const int sp = st ^ ((r >> 1) & 3);
            uint4 va;
            if (IN_BF16) va = pab[j];
            else {
                B16 o;
                o.b[0] = (__bf16)pa[j][0].x; o.b[1] = (__bf16)pa[j][0].y;
                o.b[2] = (__bf16)pa[j][0].z; o.b[3] = (__bf16)pa[j][0].w;
                o.b[4] = (__bf16)pa[j][1].x; o.b[5] = (__bf16)pa[j][1].y;
                o.b[6] = (__bf16)pa[j][1].z; o.b[7] = (__bf16)pa[j][1].w;
                va = o.u;
            }
            AB[0][r * 4 + sp] = va;
            AB[1][r * 4 + sp] = pb[j];
        }
    };

    f32x4 acc[4][4] = {};
    LOADK(0);
    WRITE();
    __syncthreads();
#pragma unroll
    for (int kk = 0; kk < 8; ++kk) {
        if (kk < 7) LOADK((kk + 1) * 32);   // prefetch next K-step into registers
        B16 af[4], bfr[4];
#pragma unroll
        for (int i = 0; i < 4; ++i) {
            const int ra = wm * 64 + i * 16 + lr;
            af[i].u = AB[0][ra * 4 + (ks4 ^ ((ra >> 1) & 3))];
            const int rb = wn * 64 + i * 16 + lr;
            bfr[i].u = AB[1][rb * 4 + (ks4 ^ ((rb >> 1) & 3))];
        }
#pragma unroll
        for (int i = 0; i < 4; ++i)
#pragma unroll
            for (int jn = 0; jn < 4; ++jn)
                acc[i][jn] = __builtin_amdgcn_mfma_f32_16x16x32_bf16(af[i].s, bfr[jn].s, acc[i][jn], 0, 0, 0);
        __syncthreads();
        if (kk < 7) {
            WRITE();
            __syncthreads();
        }
    }

    if (OUT_BF16) {
        const int er = l >> 2, ec = (l & 3) * 8;
#pragma unroll
        for (int i = 0; i < 4; ++i) {
#pragma unroll
            for (int jn = 0; jn < 4; ++jn) {
                const float bv = g.bias[col0 + wn * 64 + jn * 16 + lr];
#pragma unroll
                for (int r = 0; r < 4; ++r) {
                    union { ushort u; __bf16 b; } cv;
                    cv.b = (__bf16)(acc[i][jn][r] + bv);
                    epi[w][ks4 * 4 + r][jn * 16 + lr] = cv.u;
                }
            }
            __syncthreads();
            const int grow = row0 + wm * 64 + i * 16 + er;
            if (grow < M) {
                uint4 v0 = *(const uint4*)&epi[w][er][ec];
                uint4 v1 = *(const uint4*)&epi[w][er][ec + 32];
                bf16_t* yp = (bf16_t*)g.Y + (size_t)grow * ldY + col0 + wn * 64;
                *(uint4*)(yp + ec) = v0;
                *(uint4*)(yp + ec + 32) = v1;
            }
            __syncthreads();
        }
    } else {
        // fp32: 16 lanes x 4B = full 64B lines, direct store
        const int lq = l >> 4;
#pragma unroll
        for (int i = 0; i < 4; ++i) {
            const int rbase = row0 + wm * 64 + i * 16 + lq * 4;
#pragma unroll
            for (int jn = 0; jn < 4; ++jn) {
                const int col = col0 + wn * 64 + jn * 16 + lr;
                const float bv = g.bias[col];
#pragma unroll
                for (int r = 0; r < 4; ++r) {
                    const int grow = rbase + r;
                    if (grow < M) ((float*)g.Y)[(size_t)grow * ldY + col] = acc[i][jn][r] + bv;
                }
            }
        }
    }
}

// ---------- per-node online-softmax aggregation (2-way edge unroll) ----------
__device__ __forceinline__ float4 ldb4(const bf16_t* p) {
    bf16x4 v = *(const bf16x4*)p;
    return make_float4((float)v[0], (float)v[1], (float)v[2], (float)v[3]);
}

__device__ __forceinline__ void aggr_list(
    const bf16_t* __restrict__ K, const bf16_t* __restrict__ V, int ld,
    const int* __restrict__ rp, const int* __restrict__ srcs,
    float scaleH, int node, int lane, const float4& q, float4& accOut)
{
    const int rs = rp[node], re = rp[node + 1];
    if (rs == re) return;
    float m = NEG_INF, den = 0.f;
    float4 acc = make_float4(0.f, 0.f, 0.f, 0.f);
    int i = rs;
    for (; i + 2 <= re; i += 2) {
        const int s0 = srcs[i], s1 = srcs[i + 1];
        const float4 k0 = ldb4(K + (size_t)s0 * ld + lane * 4);
        const float4 v0 = ldb4(V + (size_t)s0 * ld + lane * 4);
        const float4 k1 = ldb4(K + (size_t)s1 * ld + lane * 4);
        const float4 v1 = ldb4(V + (size_t)s1 * ld + lane * 4);
        float d0 = q.x * k0.x + q.y * k0.y + q.z * k0.z + q.w * k0.w;
        float d1 = q.x * k1.x + q.y * k1.y + q.z * k1.z + q.w * k1.w;
        d0 += __shfl_xor(d0, 1, 64); d1 += __shfl_xor(d1, 1, 64);
        d0 += __shfl_xor(d0, 2, 64); d1 += __shfl_xor(d1, 2, 64);
        d0 += __shfl_xor(d0, 4, 64); d1 += __shfl_xor(d1, 4, 64);
        const float sc0 = d0 * scaleH, sc1 = d1 * scaleH;
        const float nm = fmaxf(m, fmaxf(sc0, sc1));
        const float r  = __expf(m - nm);
        const float p0 = __expf(sc0 - nm);
        const float p1 = __expf(sc1 - nm);
        den = den * r + p0 + p1;
        acc.x = acc.x * r + v0.x * p0 + v1.x * p1;
        acc.y = acc.y * r + v0.y * p0 + v1.y * p1;
        acc.z = acc.z * r + v0.z * p0 + v1.z * p1;
        acc.w = acc.w * r + v0.w * p0 + v1.w * p1;
        m = nm;
    }
    if (i < re) {
        const int s0 = srcs[i];
        const float4 k0 = ldb4(K + (size_t)s0 * ld + lane * 4);
        const float4 v0 = ldb4(V + (size_t)s0 * ld + lane * 4);
        float d0 = q.x * k0.x + q.y * k0.y + q.z * k0.z + q.w * k0.w;
        d0 += __shfl_xor(d0, 1, 64);
        d0 += __shfl_xor(d0, 2, 64);
        d0 += __shfl_xor(d0, 4, 64);
        const float sc0 = d0 * scaleH;
        const float nm = fmaxf(m, sc0);
        const float r  = __expf(m - nm);
        const float p0 = __expf(sc0 - nm);
        den = den * r + p0;
        acc.x = acc.x * r + v0.x * p0;
        acc.y = acc.y * r + v0.y * p0;
        acc.z = acc.z * r + v0.z * p0;
        acc.w = acc.w * r + v0.w * p0;
    }
    const float inv = 1.f / den;
    accOut.x += acc.x * inv;
    accOut.y += acc.y * inv;
    accOut.z += acc.z * inv;
    accOut.w += acc.w * inv;
}

__global__ __launch_bounds__(256) void node_aggr(
    const bf16_t* __restrict__ Qp, const bf16_t* __restrict__ Qa,
    const bf16_t* __restrict__ Yhp, const bf16_t* __restrict__ Yha,
    const int* __restrict__ rp0, const int* __restrict__ sr0,
    const int* __restrict__ rp1, const int* __restrict__ sr1,
    const int* __restrict__ rp2, const int* __restrict__ sr2,
    const float* __restrict__ rel_pri, bf16_t* __restrict__ MUb)
{
    int gid = blockIdx.x * 256 + threadIdx.x;
    int node = gid >> 6;
    if (node >= NP + NA) return;
    int lane = gid & 63;
    int h = lane >> 3;
    float4 acc = make_float4(0.f, 0.f, 0.f, 0.f);
    float scale;
    if (node < NP) {
        const float4 q = ldb4(Qp + (size_t)node * 256 + lane * 4);
        aggr_list(Yha, Yha + 256, 512,  rp0, sr0, rel_pri[h]      * INV_SQRT_DK, node, lane, q, acc);
        aggr_list(Yhp, Yhp + 256, 1024, rp1, sr1, rel_pri[8 + h]  * INV_SQRT_DK, node, lane, q, acc);
        scale = 0.5f;
    } else {
        const int n2 = node - NP;
        const float4 q = ldb4(Qa + (size_t)n2 * 256 + lane * 4);
        aggr_list(Yhp + 512, Yhp + 768, 1024, rp2, sr2, rel_pri[16 + h] * INV_SQRT_DK, n2, lane, q, acc);
        scale = 1.f;
    }
    bf16x4 o;
    o[0] = (__bf16)(acc.x * scale); o[1] = (__bf16)(acc.y * scale);
    o[2] = (__bf16)(acc.z * scale); o[3] = (__bf16)(acc.w * scale);
    *(bf16x4*)(MUb + (size_t)node * 256 + lane * 4) = o;
}

// ---------- skip-blend + LayerNorm (merged node types, in-place on d_out) ----------
__global__ __launch_bounds__(256) void out_ln(
    const float* __restrict__ O, const float* __restrict__ Tp, const float* __restrict__ Ta,
    const float* __restrict__ skip, const float* __restrict__ lns,
    const float* __restrict__ lnb, float* __restrict__ out)
{
    int gid = blockIdx.x * 256 + threadIdx.x;
    int row = gid >> 6;
    if (row >= NP + NA) return;
    int lane = gid & 63;
    const int nt = row < NP ? 0 : 1;
    const float* T = (nt == 0) ? (Tp + (size_t)row * 256) : (Ta + (size_t)(row - NP) * 256);
    float alpha = 1.f / (1.f + expf(-skip[nt]));
    float beta = 1.f - alpha;
    const float4 o4 = *(const float4*)(O + (size_t)row * 256 + lane * 4);
    const float4 t4 = *(const float4*)(T + lane * 4);
    float v[4] = { o4.x * alpha + t4.x * beta, o4.y * alpha + t4.y * beta,
                   o4.z * alpha + t4.z * beta, o4.w * alpha + t4.w * beta };
    float s = v[0] + v[1] + v[2] + v[3];
#pragma unroll
    for (int mlane = 32; mlane >= 1; mlane >>= 1) s += __shfl_xor(s, mlane, 64);
    float mean = s * (1.f / 256.f);
    float sq = 0.f;
#pragma unroll
    for (int j = 0; j < 4; ++j) { float dd = v[j] - mean; sq += dd * dd; }
#pragma unroll
    for (int mlane = 32; mlane >= 1; mlane >>= 1) sq += __shfl_xor(sq, mlane, 64);
    float rstd = rsqrtf(sq * (1.f / 256.f) + 1e-5f);
    int c = lane * 4;
    const float* ls = lns + nt * 256 + c;
    const float* lb = lnb + nt * 256 + c;
    float4 r;
    r.x = (v[0] - mean) * rstd * ls[0] + lb[0];
    r.y = (v[1] - mean) * rstd * ls[1] + lb[1];
    r.z = (v[2] - mean) * rstd * ls[2] + lb[2];
    r.w = (v[3] - mean) * rstd * ls[3] + lb[3];
    *(float4*)(out + (size_t)row * 256 + c) = r;
}

extern "C" void kernel_launch(void* const* d_in, const int* in_sizes, int n_in,
                              void* d_out, int out_size, void* d_ws, size_t ws_size,
                              hipStream_t stream) {
    const float* h_paper  = (const float*)d_in[0];
    const float* h_author = (const float*)d_in[1];
    const float* t_paper  = (const float*)d_in[2];
    const float* t_author = (const float*)d_in[3];
    const float* k_w = (const float*)d_in[4];
    const float* k_b = (const float*)d_in[5];
    const float* q_w = (const float*)d_in[6];
    const float* q_b = (const float*)d_in[7];
    const float* v_w = (const float*)d_in[8];
    const float* v_b = (const float*)d_in[9];
    const float* a_w = (const float*)d_in[10];
    const float* a_b = (const float*)d_in[11];
    const float* rel_pri = (const float*)d_in[12];
    const float* rel_att = (const float*)d_in[13];
    const float* rel_msg = (const float*)d_in[14];
    const float* skip = (const float*)d_in[15];
    const float* ln_s = (const float*)d_in[16];
    const float* ln_b = (const float*)d_in[17];
    const int* src0 = (const int*)d_in[18];
    const int* dst0 = (const int*)d_in[19];
    const int* src1 = (const int*)d_in[20];
    const int* dst1 = (const int*)d_in[21];
    const int* src2 = (const int*)d_in[22];
    const int* dst2 = (const int*)d_in[23];

    // ---- workspace layout ----
    char* base = (char*)d_ws;
    size_t off = 0;
    auto alloc = [&](size_t bytes) { char* p = base + off; off += (bytes + 255) & ~(size_t)255; return p; };
    bf16_t* Yhp  = (bf16_t*)alloc((size_t)NP * 1024 * 2);  // K1|V1|K2|V2
    bf16_t* Yha  = (bf16_t*)alloc((size_t)NA * 512 * 2);   // K0|V0
    bf16_t* Qp   = (bf16_t*)alloc((size_t)NP * 256 * 2);
    bf16_t* Qa   = (bf16_t*)alloc((size_t)NA * 256 * 2);
    bf16_t* MUb  = (bf16_t*)alloc((size_t)(NP + NA) * 256 * 2);
    bf16_t* WT_hp = (bf16_t*)alloc(1024 * 256 * 2);
    bf16_t* WT_ha = (bf16_t*)alloc(512 * 256 * 2);
    bf16_t* WT_q0 = (bf16_t*)alloc(256 * 256 * 2);
    bf16_t* WT_q1 = (bf16_t*)alloc(256 * 256 * 2);
    bf16_t* WT_a0 = (bf16_t*)alloc(256 * 256 * 2);
    bf16_t* WT_a1 = (bf16_t*)alloc(256 * 256 * 2);
    float* Bhp = (float*)alloc(1024 * 4);
    float* Bha = (float*)alloc(512 * 4);
    int* cnt0 = (int*)alloc(100000 * 4);  // cnt0,cnt1,cnt2,run0,run1,run2 contiguous
    int* cnt1 = cnt0 + 20000;
    int* cnt2 = cnt1 + 20000;
    int* run0 = cnt2 + 10000;
    int* run1 = run0 + 20000;
    int* run2 = run1 + 20000;
    int* rp0 = (int*)alloc(20001 * 4);
    int* rp1 = (int*)alloc(20001 * 4);
    int* rp2 = (int*)alloc(10001 * 4);
    int* sr0 = (int*)alloc(100000 * 4);
    int* sr1 = (int*)alloc(100000 * 4);
    int* sr2 = (int*)alloc(100000 * 4);

    const int gE = (NEDGE + 255) / 256;

    // ---- CSR build ----
    fill_u32<<<(100000 + 255) / 256, 256, 0, stream>>>((unsigned*)cnt0, 0u, 100000);
    count3<<<dim3(gE, 3), 256, 0, stream>>>(dst0, dst1, dst2, cnt0, cnt1, cnt2, NEDGE);
    scan3<<<3, 256, 0, stream>>>(cnt0, cnt1, cnt2, rp0, rp1, rp2);
    scatter3<<<dim3(gE, 3), 256, 0, stream>>>(src0, dst0, src1, dst1, src2, dst2,
                                              rp0, rp1, rp2, run0, run1, run2,
                                              sr0, sr1, sr2, NEDGE);

    // ---- weight prep (all 10 jobs in one launch) ----
    prep_weights<<<dim3(256, 10), 256, 0, stream>>>(k_w, k_b, v_w, v_b, q_w, a_w,
                                                    rel_att, rel_msg,
                                                    WT_hp, Bhp, WT_ha, Bha,
                                                    WT_q0, WT_q1, WT_a0, WT_a1);

    // ---- all projections in ONE dispatch (fp32 in, bf16 out), 4 segments, col-fastest ----
    GSegs P{};
    P.s[0] = { h_paper,  WT_hp, Bhp,       Yhp, NP, 8, 1024, 0 };
    P.s[1] = { h_author, WT_ha, Bha,       Yha, NA, 4, 512,  1256 };
    P.s[2] = { t_paper,  WT_q0, q_b,       Qp,  NP, 2, 256,  1572 };
    P.s[3] = { t_author, WT_q1, q_b + 256, Qa,  NA, 2, 256,  1886 };
    P.n = 4;
    gemm_seg<0, 1><<<2044, 256, 0, stream>>>(P);

    // ---- per-node online softmax + aggregation (bf16 out, 0.5 folded for papers) ----
    node_aggr<<<((NP + NA) * 64 + 255) / 256, 256, 0, stream>>>(
        Qp, Qa, Yhp, Yha, rp0, sr0, rp1, sr1, rp2, sr2, rel_pri, MUb);

    // ---- output linear (bf16 in, fp32 out), 2 segments ----
    float* out = (float*)d_out;
    GSegs O{};
    O.s[0] = { MUb,                    WT_a0, a_b,       out,                    NP, 2, 256, 0 };
    O.s[1] = { MUb + (size_t)NP * 256, WT_a1, a_b + 256, out + (size_t)NP * 256, NA, 2, 256, 314 };
    O.n = 2;
    gemm_seg<1, 0><<<472, 256, 0, stream>>>(O);

    // ---- skip + LayerNorm (in-place) ----
    out_ln<<<((NP + NA) * 64 + 255) / 256, 256, 0, stream>>>(out, t_paper, t_author,
                                                             skip, ln_s, ln_b, out);
}

// Round 9
// 217.315 us; speedup vs baseline: 1.1384x; 1.1384x over previous
//
#include <hip/hip_runtime.h>
#include <hip/hip_bf16.h>
#include <cstdint>
#include <cstddef>

#define NP 20000
#define NA 10000
#define NEDGE 100000
#define NEG_INF (-__builtin_huge_valf())
#define INV_SQRT_DK 0.17677669529663687f

typedef __bf16 bf16_t;
typedef __attribute__((ext_vector_type(8))) short s16x8;
typedef __attribute__((ext_vector_type(4))) float f32x4;
typedef __attribute__((ext_vector_type(4))) __bf16 bf16x4;
typedef __attribute__((ext_vector_type(8))) __bf16 bf16x8v;

union B16 { uint4 u; s16x8 s; bf16x8v b; };

typedef const __attribute__((address_space(1))) void* gas1p;
typedef __attribute__((address_space(3))) void* las3p;
#define GLD16(g, l) __builtin_amdgcn_global_load_lds((gas1p)(g), (las3p)(l), 16, 0, 0)

// ---------- fill ----------
__global__ __launch_bounds__(256) void fill_u32(unsigned* __restrict__ p, unsigned v, int n) {
    int i = blockIdx.x * 256 + threadIdx.x;
    if (i < n) p[i] = v;
}

// ---------- fp32 -> bf16, 4 tensors in one launch ----------
__global__ __launch_bounds__(256) void f2b4(
    const float* __restrict__ s0, bf16_t* __restrict__ d0, int n0,
    const float* __restrict__ s1, bf16_t* __restrict__ d1, int n1,
    const float* __restrict__ s2, bf16_t* __restrict__ d2, int n2,
    const float* __restrict__ s3, bf16_t* __restrict__ d3, int n3)
{
    const float* s; bf16_t* d; int n;
    switch (blockIdx.y) { case 0: s = s0; d = d0; n = n0; break;
                          case 1: s = s1; d = d1; n = n1; break;
                          case 2: s = s2; d = d2; n = n2; break;
                          default: s = s3; d = d3; n = n3; }
    int i = blockIdx.x * 256 + threadIdx.x;   // index of 8-elem group
    if (i >= n) return;
    const float* sp = s + (size_t)i * 8;
    float4 x0 = *(const float4*)sp;
    float4 x1 = *(const float4*)(sp + 4);
    B16 o;
    o.b[0] = (__bf16)x0.x; o.b[1] = (__bf16)x0.y; o.b[2] = (__bf16)x0.z; o.b[3] = (__bf16)x0.w;
    o.b[4] = (__bf16)x1.x; o.b[5] = (__bf16)x1.y; o.b[6] = (__bf16)x1.z; o.b[7] = (__bf16)x1.w;
    *(uint4*)(d + (size_t)i * 8) = o.u;
}

// ---------- CSR build (3 etypes per launch) ----------
__global__ __launch_bounds__(256) void count3(
    const int* __restrict__ d0, const int* __restrict__ d1, const int* __restrict__ d2,
    int* __restrict__ c0, int* __restrict__ c1, int* __restrict__ c2, int E)
{
    int e = blockIdx.x * 256 + threadIdx.x;
    if (e >= E) return;
    const int* d; int* c;
    switch (blockIdx.y) { case 0: d = d0; c = c0; break; case 1: d = d1; c = c1; break; default: d = d2; c = c2; }
    atomicAdd(c + d[e], 1);
}

__global__ __launch_bounds__(256) void scan3(
    const int* __restrict__ c0, const int* __restrict__ c1, const int* __restrict__ c2,
    int* __restrict__ r0, int* __restrict__ r1, int* __restrict__ r2)
{
    const int* cnt; int* rp; int n;
    switch (blockIdx.x) { case 0: cnt = c0; rp = r0; n = NP; break;
                          case 1: cnt = c1; rp = r1; n = NP; break;
                          default: cnt = c2; rp = r2; n = NA; }
    __shared__ int sums[256];
    __shared__ int offs[257];
    const int t = threadIdx.x;
    const int chunk = (n + 255) / 256;
    const int lo = min(t * chunk, n), hi = min(lo + chunk, n);
    int s = 0;
    for (int i = lo; i < hi; ++i) s += cnt[i];
    sums[t] = s;
    __syncthreads();
    if (t == 0) {
        int a = 0;
        for (int i = 0; i < 256; ++i) { offs[i] = a; a += sums[i]; }
        rp[n] = a;
    }
    __syncthreads();
    int a = offs[t];
    for (int i = lo; i < hi; ++i) { rp[i] = a; a += cnt[i]; }
}

__global__ __launch_bounds__(256) void scatter3(
    const int* __restrict__ s0, const int* __restrict__ d0,
    const int* __restrict__ s1, const int* __restrict__ d1,
    const int* __restrict__ s2, const int* __restrict__ d2,
    const int* __restrict__ r0, const int* __restrict__ r1, const int* __restrict__ r2,
    int* __restrict__ run0, int* __restrict__ run1, int* __restrict__ run2,
    int* __restrict__ sr0, int* __restrict__ sr1, int* __restrict__ sr2, int E)
{
    int e = blockIdx.x * 256 + threadIdx.x;
    if (e >= E) return;
    const int *src, *dst, *rp; int *run, *srs;
    switch (blockIdx.y) {
        case 0: src = s0; dst = d0; rp = r0; run = run0; srs = sr0; break;
        case 1: src = s1; dst = d1; rp = r1; run = run1; srs = sr1; break;
        default: src = s2; dst = d2; rp = r2; run = run2; srs = sr2;
    }
    int d = dst[e];
    int pos = atomicAdd(run + d, 1);
    srs[rp[d] + pos] = src[e];
}

// ---------- weight prep: 6 fused (proj x rel) + 4 plain transposes, all bf16 transposed ----------
__global__ __launch_bounds__(256) void prep_weights(
    const float* __restrict__ k_w, const float* __restrict__ k_b,
    const float* __restrict__ v_w, const float* __restrict__ v_b,
    const float* __restrict__ q_w, const float* __restrict__ a_w,
    const float* __restrict__ rel_att, const float* __restrict__ rel_msg,
    bf16_t* __restrict__ WT_hp, float* __restrict__ Bhp,
    bf16_t* __restrict__ WT_ha, float* __restrict__ Bha,
    bf16_t* __restrict__ WT_q0, bf16_t* __restrict__ WT_q1,
    bf16_t* __restrict__ WT_a0, bf16_t* __restrict__ WT_a1)
{
    const int y = blockIdx.y;
    const int c = blockIdx.x;
    const int t = threadIdx.x;
    if (y < 6) {
        const float *W, *b, *R; bf16_t* WT; float* bias;
        switch (y) {
            case 0: W = k_w;         b = k_b;       R = rel_att + 8192;  WT = WT_hp;          bias = Bhp;       break;
            case 1: W = v_w;         b = v_b;       R = rel_msg + 8192;  WT = WT_hp + 65536;  bias = Bhp + 256; break;
            case 2: W = k_w;         b = k_b;       R = rel_att + 16384; WT = WT_hp + 131072; bias = Bhp + 512; break;
            case 3: W = v_w;         b = v_b;       R = rel_msg + 16384; WT = WT_hp + 196608; bias = Bhp + 768; break;
            case 4: W = k_w + 65536; b = k_b + 256; R = rel_att;         WT = WT_ha;          bias = Bha;       break;
            default:W = v_w + 65536; b = v_b + 256; R = rel_msg;         WT = WT_ha + 65536;  bias = Bha + 256;
        }
        __shared__ float rs[32];
        const int h = c >> 5, e = c & 31;
        if (t < 32) rs[t] = R[(h * 32 + t) * 32 + e];
        __syncthreads();
        float s = 0.f;
#pragma unroll
        for (int d = 0; d < 32; ++d) s += W[t * 256 + h * 32 + d] * rs[d];
        WT[c * 256 + t] = (bf16_t)s;
        if (t == 0) {
            float sb = 0.f;
#pragma unroll
            for (int d = 0; d < 32; ++d) sb += b[h * 32 + d] * rs[d];
            bias[c] = sb;
        }
    } else {
        const float* W; bf16_t* WT;
        switch (y) { case 6: W = q_w; WT = WT_q0; break;
                     case 7: W = q_w + 65536; WT = WT_q1; break;
                     case 8: W = a_w; WT = WT_a0; break;
                     default: W = a_w + 65536; WT = WT_a1; }
        WT[c * 256 + t] = (bf16_t)W[t * 256 + c];
    }
}

// ---------- segmented bf16 MFMA GEMM, global_load_lds staging (m97 structure) ----------
// Y[M,ldY] = X[M,256] @ WT^T + bias. X bf16 [>=ceil128(M)][256] (padded rows readable),
// WT bf16 [N][256]. LDS linear dest + pre-swizzled global source; 2 barriers/K-step.
struct GSeg {
    const bf16_t* X; const bf16_t* WT; const float* bias; void* Y;
    int M, ncb, ldY, blk0;
};
struct GSegs { GSeg s[4]; int n; };

template<int OUT_BF16>
__global__ __launch_bounds__(256) void gemm_seg(GSegs segs)
{
    int si = 0;
#pragma unroll
    for (int i = 1; i < 4; ++i)
        if (i < segs.n && (int)blockIdx.x >= segs.s[i].blk0) si = i;
    const GSeg g = segs.s[si];
    const int lid = blockIdx.x - g.blk0;
    const int by = lid % g.ncb;
    const int bx = lid / g.ncb;
    const int row0 = bx * 128, col0 = by * 128;
    const int M = g.M, ldY = g.ldY;

    __shared__ uint4 As[512];   // word idx = r*4 + sp, sp = s ^ ((r>>1)&3)  (8 KB)
    __shared__ uint4 Bs[512];
    __shared__ ushort epi[4][16][OUT_BF16 ? 72 : 2];
    const int t = threadIdx.x;
    const int w = t >> 6, l = t & 63;
    const int wm = w >> 1, wn = w & 1;
    const int lr = l & 15, ks4 = l >> 4;

    // staging: thread covers word idx = w*128 + c*64 + l, c in {0,1}; LDS dest linear,
    // global source pre-swizzled so LDS word (r, sp) holds k-slot s = sp ^ ((r>>1)&3).
    const bf16_t* gA[2]; const bf16_t* gB[2];
    uint4* lA[2]; uint4* lB[2];
#pragma unroll
    for (int c = 0; c < 2; ++c) {
        const int idx = w * 128 + c * 64 + l;
        const int r = idx >> 2;
        const int s = (idx & 3) ^ ((r >> 1) & 3);
        gA[c] = g.X  + (size_t)(row0 + r) * 256 + s * 8;
        gB[c] = g.WT + (size_t)(col0 + r) * 256 + s * 8;
        lA[c] = As + w * 128 + c * 64;   // wave-uniform base (lane x 16B implicit)
        lB[c] = Bs + w * 128 + c * 64;
    }

    f32x4 acc[4][4] = {};
#pragma unroll
    for (int kk = 0; kk < 8; ++kk) {
        if (kk) __syncthreads();                 // prev iter's ds_reads done
        GLD16(gA[0] + kk * 32, lA[0]);
        GLD16(gB[0] + kk * 32, lB[0]);
        GLD16(gA[1] + kk * 32, lA[1]);
        GLD16(gB[1] + kk * 32, lB[1]);
        __syncthreads();                          // compiler drains vmcnt before barrier
        B16 af[4], bfr[4];
#pragma unroll
        for (int i = 0; i < 4; ++i) {
            const int ra = wm * 64 + i * 16 + lr;
            af[i].u = As[ra * 4 + (ks4 ^ ((ra >> 1) & 3))];
            const int rb = wn * 64 + i * 16 + lr;
            bfr[i].u = Bs[rb * 4 + (ks4 ^ ((rb >> 1) & 3))];
        }
#pragma unroll
        for (int i = 0; i < 4; ++i)
#pragma unroll
            for (int jn = 0; jn < 4; ++jn)
                acc[i][jn] = __builtin_amdgcn_mfma_f32_16x16x32_bf16(af[i].s, bfr[jn].s, acc[i][jn], 0, 0, 0);
    }

    if (OUT_BF16) {
        const int er = l >> 2, ec = (l & 3) * 8;
#pragma unroll
        for (int i = 0; i < 4; ++i) {
            __syncthreads();
#pragma unroll
            for (int jn = 0; jn < 4; ++jn) {
                const float bv = g.bias[col0 + wn * 64 + jn * 16 + lr];
#pragma unroll
                for (int r = 0; r < 4; ++r) {
                    union { ushort u; __bf16 b; } cv;
                    cv.b = (__bf16)(acc[i][jn][r] + bv);
                    epi[w][ks4 * 4 + r][jn * 16 + lr] = cv.u;
                }
            }
            __syncthreads();
            const int grow = row0 + wm * 64 + i * 16 + er;
            if (grow < M) {
                uint4 v0 = *(const uint4*)&epi[w][er][ec];
                uint4 v1 = *(const uint4*)&epi[w][er][ec + 32];
                bf16_t* yp = (bf16_t*)g.Y + (size_t)grow * ldY + col0 + wn * 64;
                *(uint4*)(yp + ec) = v0;
                *(uint4*)(yp + ec + 32) = v1;
            }
        }
    } else {
        const int lq = l >> 4;
#pragma unroll
        for (int i = 0; i < 4; ++i) {
            const int rbase = row0 + wm * 64 + i * 16 + lq * 4;
#pragma unroll
            for (int jn = 0; jn < 4; ++jn) {
                const int col = col0 + wn * 64 + jn * 16 + lr;
                const float bv = g.bias[col];
#pragma unroll
                for (int r = 0; r < 4; ++r) {
                    const int grow = rbase + r;
                    if (grow < M) ((float*)g.Y)[(size_t)grow * ldY + col] = acc[i][jn][r] + bv;
                }
            }
        }
    }
}

// ---------- per-node online-softmax aggregation (2-way edge unroll) ----------
__device__ __forceinline__ float4 ldb4(const bf16_t* p) {
    bf16x4 v = *(const bf16x4*)p;
    return make_float4((float)v[0], (float)v[1], (float)v[2], (float)v[3]);
}

__device__ __forceinline__ void aggr_list(
    const bf16_t* __restrict__ K, const bf16_t* __restrict__ V, int ld,
    const int* __restrict__ rp, const int* __restrict__ srcs,
    float scaleH, int node, int lane, const float4& q, float4& accOut)
{
    const int rs = rp[node], re = rp[node + 1];
    if (rs == re) return;
    float m = NEG_INF, den = 0.f;
    float4 acc = make_float4(0.f, 0.f, 0.f, 0.f);
    int i = rs;
    for (; i + 2 <= re; i += 2) {
        const int s0 = srcs[i], s1 = srcs[i + 1];
        const float4 k0 = ldb4(K + (size_t)s0 * ld + lane * 4);
        const float4 v0 = ldb4(V + (size_t)s0 * ld + lane * 4);
        const float4 k1 = ldb4(K + (size_t)s1 * ld + lane * 4);
        const float4 v1 = ldb4(V + (size_t)s1 * ld + lane * 4);
        float d0 = q.x * k0.x + q.y * k0.y + q.z * k0.z + q.w * k0.w;
        float d1 = q.x * k1.x + q.y * k1.y + q.z * k1.z + q.w * k1.w;
        d0 += __shfl_xor(d0, 1, 64); d1 += __shfl_xor(d1, 1, 64);
        d0 += __shfl_xor(d0, 2, 64); d1 += __shfl_xor(d1, 2, 64);
        d0 += __shfl_xor(d0, 4, 64); d1 += __shfl_xor(d1, 4, 64);
        const float sc0 = d0 * scaleH, sc1 = d1 * scaleH;
        const float nm = fmaxf(m, fmaxf(sc0, sc1));
        const float r  = __expf(m - nm);
        const float p0 = __expf(sc0 - nm);
        const float p1 = __expf(sc1 - nm);
        den = den * r + p0 + p1;
        acc.x = acc.x * r + v0.x * p0 + v1.x * p1;
        acc.y = acc.y * r + v0.y * p0 + v1.y * p1;
        acc.z = acc.z * r + v0.z * p0 + v1.z * p1;
        acc.w = acc.w * r + v0.w * p0 + v1.w * p1;
        m = nm;
    }
    if (i < re) {
        const int s0 = srcs[i];
        const float4 k0 = ldb4(K + (size_t)s0 * ld + lane * 4);
        const float4 v0 = ldb4(V + (size_t)s0 * ld + lane * 4);
        float d0 = q.x * k0.x + q.y * k0.y + q.z * k0.z + q.w * k0.w;
        d0 += __shfl_xor(d0, 1, 64);
        d0 += __shfl_xor(d0, 2, 64);
        d0 += __shfl_xor(d0, 4, 64);
        const float sc0 = d0 * scaleH;
        const float nm = fmaxf(m, sc0);
        const float r  = __expf(m - nm);
        const float p0 = __expf(sc0 - nm);
        den = den * r + p0;
        acc.x = acc.x * r + v0.x * p0;
        acc.y = acc.y * r + v0.y * p0;
        acc.z = acc.z * r + v0.z * p0;
        acc.w = acc.w * r + v0.w * p0;
    }
    const float inv = 1.f / den;
    accOut.x += acc.x * inv;
    accOut.y += acc.y * inv;
    accOut.z += acc.z * inv;
    accOut.w += acc.w * inv;
}

__global__ __launch_bounds__(256) void node_aggr(
    const bf16_t* __restrict__ Qp, const bf16_t* __restrict__ Qa,
    const bf16_t* __restrict__ Yhp, const bf16_t* __restrict__ Yha,
    const int* __restrict__ rp0, const int* __restrict__ sr0,
    const int* __restrict__ rp1, const int* __restrict__ sr1,
    const int* __restrict__ rp2, const int* __restrict__ sr2,
    const float* __restrict__ rel_pri, bf16_t* __restrict__ MUb)
{
    int gid = blockIdx.x * 256 + threadIdx.x;
    int node = gid >> 6;
    if (node >= NP + NA) return;
    int lane = gid & 63;
    int h = lane >> 3;
    float4 acc = make_float4(0.f, 0.f, 0.f, 0.f);
    float scale;
    if (node < NP) {
        const float4 q = ldb4(Qp + (size_t)node * 256 + lane * 4);
        aggr_list(Yha, Yha + 256, 512,  rp0, sr0, rel_pri[h]      * INV_SQRT_DK, node, lane, q, acc);
        aggr_list(Yhp, Yhp + 256, 1024, rp1, sr1, rel_pri[8 + h]  * INV_SQRT_DK, node, lane, q, acc);
        scale = 0.5f;
    } else {
        const int n2 = node - NP;
        const float4 q = ldb4(Qa + (size_t)n2 * 256 + lane * 4);
        aggr_list(Yhp + 512, Yhp + 768, 1024, rp2, sr2, rel_pri[16 + h] * INV_SQRT_DK, n2, lane, q, acc);
        scale = 1.f;
    }
    bf16x4 o;
    o[0] = (__bf16)(acc.x * scale); o[1] = (__bf16)(acc.y * scale);
    o[2] = (__bf16)(acc.z * scale); o[3] = (__bf16)(acc.w * scale);
    *(bf16x4*)(MUb + (size_t)node * 256 + lane * 4) = o;
}

// ---------- skip-blend + LayerNorm (merged node types, in-place on d_out) ----------
__global__ __launch_bounds__(256) void out_ln(
    const float* __restrict__ O, const float* __restrict__ Tp, const float* __restrict__ Ta,
    const float* __restrict__ skip, const float* __restrict__ lns,
    const float* __restrict__ lnb, float* __restrict__ out)
{
    int gid = blockIdx.x * 256 + threadIdx.x;
    int row = gid >> 6;
    if (row >= NP + NA) return;
    int lane = gid & 63;
    const int nt = row < NP ? 0 : 1;
    const float* T = (nt == 0) ? (Tp + (size_t)row * 256) : (Ta + (size_t)(row - NP) * 256);
    float alpha = 1.f / (1.f + expf(-skip[nt]));
    float beta = 1.f - alpha;
    const float4 o4 = *(const float4*)(O + (size_t)row * 256 + lane * 4);
    const float4 t4 = *(const float4*)(T + lane * 4);
    float v[4] = { o4.x * alpha + t4.x * beta, o4.y * alpha + t4.y * beta,
                   o4.z * alpha + t4.z * beta, o4.w * alpha + t4.w * beta };
    float s = v[0] + v[1] + v[2] + v[3];
#pragma unroll
    for (int mlane = 32; mlane >= 1; mlane >>= 1) s += __shfl_xor(s, mlane, 64);
    float mean = s * (1.f / 256.f);
    float sq = 0.f;
#pragma unroll
    for (int j = 0; j < 4; ++j) { float dd = v[j] - mean; sq += dd * dd; }
#pragma unroll
    for (int mlane = 32; mlane >= 1; mlane >>= 1) sq += __shfl_xor(sq, mlane, 64);
    float rstd = rsqrtf(sq * (1.f / 256.f) + 1e-5f);
    int c = lane * 4;
    const float* ls = lns + nt * 256 + c;
    const float* lb = lnb + nt * 256 + c;
    float4 r;
    r.x = (v[0] - mean) * rstd * ls[0] + lb[0];
    r.y = (v[1] - mean) * rstd * ls[1] + lb[1];
    r.z = (v[2] - mean) * rstd * ls[2] + lb[2];
    r.w = (v[3] - mean) * rstd * ls[3] + lb[3];
    *(float4*)(out + (size_t)row * 256 + c) = r;
}

extern "C" void kernel_launch(void* const* d_in, const int* in_sizes, int n_in,
                              void* d_out, int out_size, void* d_ws, size_t ws_size,
                              hipStream_t stream) {
    const float* h_paper  = (const float*)d_in[0];
    const float* h_author = (const float*)d_in[1];
    const float* t_paper  = (const float*)d_in[2];
    const float* t_author = (const float*)d_in[3];
    const float* k_w = (const float*)d_in[4];
    const float* k_b = (const float*)d_in[5];
    const float* q_w = (const float*)d_in[6];
    const float* q_b = (const float*)d_in[7];
    const float* v_w = (const float*)d_in[8];
    const float* v_b = (const float*)d_in[9];
    const float* a_w = (const float*)d_in[10];
    const float* a_b = (const float*)d_in[11];
    const float* rel_pri = (const float*)d_in[12];
    const float* rel_att = (const float*)d_in[13];
    const float* rel_msg = (const float*)d_in[14];
    const float* skip = (const float*)d_in[15];
    const float* ln_s = (const float*)d_in[16];
    const float* ln_b = (const float*)d_in[17];
    const int* src0 = (const int*)d_in[18];
    const int* dst0 = (const int*)d_in[19];
    const int* src1 = (const int*)d_in[20];
    const int* dst1 = (const int*)d_in[21];
    const int* src2 = (const int*)d_in[22];
    const int* dst2 = (const int*)d_in[23];

    // padded row counts (multiples of 128) so GEMM staging never reads unmapped memory
    const int NPpad = 20096, NApad = 10112;

    // ---- workspace layout ----
    char* base = (char*)d_ws;
    size_t off = 0;
    auto alloc = [&](size_t bytes) { char* p = base + off; off += (bytes + 255) & ~(size_t)255; return p; };
    bf16_t* Xhp  = (bf16_t*)alloc((size_t)NPpad * 256 * 2);
    bf16_t* Xha  = (bf16_t*)alloc((size_t)NApad * 256 * 2);
    bf16_t* Xtp  = (bf16_t*)alloc((size_t)NPpad * 256 * 2);
    bf16_t* Xta  = (bf16_t*)alloc((size_t)NApad * 256 * 2);
    bf16_t* Yhp  = (bf16_t*)alloc((size_t)NP * 1024 * 2);  // K1|V1|K2|V2
    bf16_t* Yha  = (bf16_t*)alloc((size_t)NA * 512 * 2);   // K0|V0
    bf16_t* Qp   = (bf16_t*)alloc((size_t)NP * 256 * 2);
    bf16_t* Qa   = (bf16_t*)alloc((size_t)NA * 256 * 2);
    bf16_t* MUb  = (bf16_t*)alloc((size_t)(NP + NApad) * 256 * 2);  // padded tail
    bf16_t* WT_hp = (bf16_t*)alloc(1024 * 256 * 2);
    bf16_t* WT_ha = (bf16_t*)alloc(512 * 256 * 2);
    bf16_t* WT_q0 = (bf16_t*)alloc(256 * 256 * 2);
    bf16_t* WT_q1 = (bf16_t*)alloc(256 * 256 * 2);
    bf16_t* WT_a0 = (bf16_t*)alloc(256 * 256 * 2);
    bf16_t* WT_a1 = (bf16_t*)alloc(256 * 256 * 2);
    float* Bhp = (float*)alloc(1024 * 4);
    float* Bha = (float*)alloc(512 * 4);
    int* cnt0 = (int*)alloc(100000 * 4);  // cnt0,cnt1,cnt2,run0,run1,run2 contiguous
    int* cnt1 = cnt0 + 20000;
    int* cnt2 = cnt1 + 20000;
    int* run0 = cnt2 + 10000;
    int* run1 = run0 + 20000;
    int* run2 = run1 + 20000;
    int* rp0 = (int*)alloc(20001 * 4);
    int* rp1 = (int*)alloc(20001 * 4);
    int* rp2 = (int*)alloc(10001 * 4);
    int* sr0 = (int*)alloc(100000 * 4);
    int* sr1 = (int*)alloc(100000 * 4);
    int* sr2 = (int*)alloc(100000 * 4);

    const int gE = (NEDGE + 255) / 256;

    // ---- CSR build ----
    fill_u32<<<(100000 + 255) / 256, 256, 0, stream>>>((unsigned*)cnt0, 0u, 100000);
    count3<<<dim3(gE, 3), 256, 0, stream>>>(dst0, dst1, dst2, cnt0, cnt1, cnt2, NEDGE);
    scan3<<<3, 256, 0, stream>>>(cnt0, cnt1, cnt2, rp0, rp1, rp2);
    scatter3<<<dim3(gE, 3), 256, 0, stream>>>(src0, dst0, src1, dst1, src2, dst2,
                                              rp0, rp1, rp2, run0, run1, run2,
                                              sr0, sr1, sr2, NEDGE);

    // ---- weight prep ----
    prep_weights<<<dim3(256, 10), 256, 0, stream>>>(k_w, k_b, v_w, v_b, q_w, a_w,
                                                    rel_att, rel_msg,
                                                    WT_hp, Bhp, WT_ha, Bha,
                                                    WT_q0, WT_q1, WT_a0, WT_a1);

    // ---- X fp32 -> bf16 (one launch, 4 tensors) ----
    f2b4<<<dim3(2500, 4), 256, 0, stream>>>(h_paper,  Xhp, NP * 32,
                                            h_author, Xha, NA * 32,
                                            t_paper,  Xtp, NP * 32,
                                            t_author, Xta, NA * 32);

    // ---- all projections in ONE dispatch (bf16 in/out), 4 segments ----
    GSegs P{};
    P.s[0] = { Xhp, WT_hp, Bhp,       Yhp, NP, 8, 1024, 0 };
    P.s[1] = { Xha, WT_ha, Bha,       Yha, NA, 4, 512,  1256 };
    P.s[2] = { Xtp, WT_q0, q_b,       Qp,  NP, 2, 256,  1572 };
    P.s[3] = { Xta, WT_q1, q_b + 256, Qa,  NA, 2, 256,  1886 };
    P.n = 4;
    gemm_seg<1><<<2044, 256, 0, stream>>>(P);

    // ---- per-node online softmax + aggregation (bf16 out, 0.5 folded for papers) ----
    node_aggr<<<((NP + NA) * 64 + 255) / 256, 256, 0, stream>>>(
        Qp, Qa, Yhp, Yha, rp0, sr0, rp1, sr1, rp2, sr2, rel_pri, MUb);

    // ---- output linear (bf16 in, fp32 out), 2 segments ----
    float* out = (float*)d_out;
    GSegs O{};
    O.s[0] = { MUb,                    WT_a0, a_b,       out,                    NP, 2, 256, 0 };
    O.s[1] = { MUb + (size_t)NP * 256, WT_a1, a_b + 256, out + (size_t)NP * 256, NA, 2, 256, 314 };
    O.n = 2;
    gemm_seg<0><<<472, 256, 0, stream>>>(O);

    // ---- skip + LayerNorm (in-place) ----
    out_ln<<<((NP + NA) * 64 + 255) / 256, 256, 0, stream>>>(out, t_paper, t_author,
                                                             skip, ln_s, ln_b, out);
}

// Round 10
// 212.242 us; speedup vs baseline: 1.1657x; 1.0239x over previous
//
#include <hip/hip_runtime.h>
#include <hip/hip_bf16.h>
#include <cstdint>
#include <cstddef>

#define NP 20000
#define NA 10000
#define NEDGE 100000
#define NEG_INF (-__builtin_huge_valf())
#define INV_SQRT_DK 0.17677669529663687f

typedef __bf16 bf16_t;
typedef __attribute__((ext_vector_type(8))) short s16x8;
typedef __attribute__((ext_vector_type(4))) float f32x4;
typedef __attribute__((ext_vector_type(4))) __bf16 bf16x4;
typedef __attribute__((ext_vector_type(8))) __bf16 bf16x8v;

union B16 { uint4 u; s16x8 s; bf16x8v b; };

typedef const __attribute__((address_space(1))) void* gas1p;
typedef __attribute__((address_space(3))) void* las3p;
#define GLD16(g, l) __builtin_amdgcn_global_load_lds((gas1p)(g), (las3p)(l), 16, 0, 0)

// ---------- fp32 -> bf16, 4 tensors in one launch ----------
__global__ __launch_bounds__(256) void f2b4(
    const float* __restrict__ s0, bf16_t* __restrict__ d0, int n0,
    const float* __restrict__ s1, bf16_t* __restrict__ d1, int n1,
    const float* __restrict__ s2, bf16_t* __restrict__ d2, int n2,
    const float* __restrict__ s3, bf16_t* __restrict__ d3, int n3)
{
    const float* s; bf16_t* d; int n;
    switch (blockIdx.y) { case 0: s = s0; d = d0; n = n0; break;
                          case 1: s = s1; d = d1; n = n1; break;
                          case 2: s = s2; d = d2; n = n2; break;
                          default: s = s3; d = d3; n = n3; }
    int i = blockIdx.x * 256 + threadIdx.x;   // index of 8-elem group
    if (i >= n) return;
    const float* sp = s + (size_t)i * 8;
    float4 x0 = *(const float4*)sp;
    float4 x1 = *(const float4*)(sp + 4);
    B16 o;
    o.b[0] = (__bf16)x0.x; o.b[1] = (__bf16)x0.y; o.b[2] = (__bf16)x0.z; o.b[3] = (__bf16)x0.w;
    o.b[4] = (__bf16)x1.x; o.b[5] = (__bf16)x1.y; o.b[6] = (__bf16)x1.z; o.b[7] = (__bf16)x1.w;
    *(uint4*)(d + (size_t)i * 8) = o.u;
}

// ---------- CSR build (3 etypes per launch) ----------
__global__ __launch_bounds__(256) void count3(
    const int* __restrict__ d0, const int* __restrict__ d1, const int* __restrict__ d2,
    int* __restrict__ c0, int* __restrict__ c1, int* __restrict__ c2, int E)
{
    int e = blockIdx.x * 256 + threadIdx.x;
    if (e >= E) return;
    const int* d; int* c;
    switch (blockIdx.y) { case 0: d = d0; c = c0; break; case 1: d = d1; c = c1; break; default: d = d2; c = c2; }
    atomicAdd(c + d[e], 1);
}

__global__ __launch_bounds__(256) void scan3(
    const int* __restrict__ c0, const int* __restrict__ c1, const int* __restrict__ c2,
    int* __restrict__ r0, int* __restrict__ r1, int* __restrict__ r2)
{
    const int* cnt; int* rp; int n;
    switch (blockIdx.x) { case 0: cnt = c0; rp = r0; n = NP; break;
                          case 1: cnt = c1; rp = r1; n = NP; break;
                          default: cnt = c2; rp = r2; n = NA; }
    __shared__ int sums[256];
    __shared__ int offs[257];
    const int t = threadIdx.x;
    const int chunk = (n + 255) / 256;
    const int lo = min(t * chunk, n), hi = min(lo + chunk, n);
    int s = 0;
    for (int i = lo; i < hi; ++i) s += cnt[i];
    sums[t] = s;
    __syncthreads();
    if (t == 0) {
        int a = 0;
        for (int i = 0; i < 256; ++i) { offs[i] = a; a += sums[i]; }
        rp[n] = a;
    }
    __syncthreads();
    int a = offs[t];
    for (int i = lo; i < hi; ++i) { rp[i] = a; a += cnt[i]; }
}

__global__ __launch_bounds__(256) void scatter3(
    const int* __restrict__ s0, const int* __restrict__ d0,
    const int* __restrict__ s1, const int* __restrict__ d1,
    const int* __restrict__ s2, const int* __restrict__ d2,
    const int* __restrict__ r0, const int* __restrict__ r1, const int* __restrict__ r2,
    int* __restrict__ run0, int* __restrict__ run1, int* __restrict__ run2,
    int* __restrict__ sr0, int* __restrict__ sr1, int* __restrict__ sr2, int E)
{
    int e = blockIdx.x * 256 + threadIdx.x;
    if (e >= E) return;
    const int *src, *dst, *rp; int *run, *srs;
    switch (blockIdx.y) {
        case 0: src = s0; dst = d0; rp = r0; run = run0; srs = sr0; break;
        case 1: src = s1; dst = d1; rp = r1; run = run1; srs = sr1; break;
        default: src = s2; dst = d2; rp = r2; run = run2; srs = sr2;
    }
    int d = dst[e];
    int pos = atomicAdd(run + d, 1);
    srs[rp[d] + pos] = src[e];
}

// ---------- weight prep: 6 fused + 4 transposes + cnt-zero job (y=10) ----------
__global__ __launch_bounds__(256) void prep_weights(
    const float* __restrict__ k_w, const float* __restrict__ k_b,
    const float* __restrict__ v_w, const float* __restrict__ v_b,
    const float* __restrict__ q_w, const float* __restrict__ a_w,
    const float* __restrict__ rel_att, const float* __restrict__ rel_msg,
    bf16_t* __restrict__ WT_hp, float* __restrict__ Bhp,
    bf16_t* __restrict__ WT_ha, float* __restrict__ Bha,
    bf16_t* __restrict__ WT_q0, bf16_t* __restrict__ WT_q1,
    bf16_t* __restrict__ WT_a0, bf16_t* __restrict__ WT_a1,
    int* __restrict__ cntz)
{
    const int y = blockIdx.y;
    const int c = blockIdx.x;
    const int t = threadIdx.x;
    if (y == 10) {
        const int idx = c * 256 + t;
        if (idx < 100000) cntz[idx] = 0;
        const int idx2 = idx + 65536;
        if (idx2 < 100000) cntz[idx2] = 0;
        return;
    }
    if (y < 6) {
        const float *W, *b, *R; bf16_t* WT; float* bias;
        switch (y) {
            case 0: W = k_w;         b = k_b;       R = rel_att + 8192;  WT = WT_hp;          bias = Bhp;       break;
            case 1: W = v_w;         b = v_b;       R = rel_msg + 8192;  WT = WT_hp + 65536;  bias = Bhp + 256; break;
            case 2: W = k_w;         b = k_b;       R = rel_att + 16384; WT = WT_hp + 131072; bias = Bhp + 512; break;
            case 3: W = v_w;         b = v_b;       R = rel_msg + 16384; WT = WT_hp + 196608; bias = Bhp + 768; break;
            case 4: W = k_w + 65536; b = k_b + 256; R = rel_att;         WT = WT_ha;          bias = Bha;       break;
            default:W = v_w + 65536; b = v_b + 256; R = rel_msg;         WT = WT_ha + 65536;  bias = Bha + 256;
        }
        __shared__ float rs[32];
        const int h = c >> 5, e = c & 31;
        if (t < 32) rs[t] = R[(h * 32 + t) * 32 + e];
        __syncthreads();
        float s = 0.f;
#pragma unroll
        for (int d = 0; d < 32; ++d) s += W[t * 256 + h * 32 + d] * rs[d];
        WT[c * 256 + t] = (bf16_t)s;
        if (t == 0) {
            float sb = 0.f;
#pragma unroll
            for (int d = 0; d < 32; ++d) sb += b[h * 32 + d] * rs[d];
            bias[c] = sb;
        }
    } else {
        const float* W; bf16_t* WT;
        switch (y) { case 6: W = q_w; WT = WT_q0; break;
                     case 7: W = q_w + 65536; WT = WT_q1; break;
                     case 8: W = a_w; WT = WT_a0; break;
                     default: W = a_w + 65536; WT = WT_a1; }
        WT[c * 256 + t] = (bf16_t)W[t * 256 + c];
    }
}

// ---------- segmented bf16 MFMA GEMM, global_load_lds staging (m97 structure) ----------
struct GSeg {
    const bf16_t* X; const bf16_t* WT; const float* bias; void* Y;
    int M, ncb, ldY, blk0;
};
struct GSegs { GSeg s[4]; int n; };

template<int OUT_BF16>
__global__ __launch_bounds__(256) void gemm_seg(GSegs segs)
{
    int si = 0;
#pragma unroll
    for (int i = 1; i < 4; ++i)
        if (i < segs.n && (int)blockIdx.x >= segs.s[i].blk0) si = i;
    const GSeg g = segs.s[si];
    const int lid = blockIdx.x - g.blk0;
    const int by = lid % g.ncb;
    const int bx = lid / g.ncb;
    const int row0 = bx * 128, col0 = by * 128;
    const int M = g.M, ldY = g.ldY;

    __shared__ uint4 As[512];   // word idx = r*4 + sp, sp = s ^ ((r>>1)&3)  (8 KB)
    __shared__ uint4 Bs[512];
    __shared__ ushort epi[4][16][OUT_BF16 ? 72 : 2];
    const int t = threadIdx.x;
    const int w = t >> 6, l = t & 63;
    const int wm = w >> 1, wn = w & 1;
    const int lr = l & 15, ks4 = l >> 4;

    const bf16_t* gA[2]; const bf16_t* gB[2];
    uint4* lA[2]; uint4* lB[2];
#pragma unroll
    for (int c = 0; c < 2; ++c) {
        const int idx = w * 128 + c * 64 + l;
        const int r = idx >> 2;
        const int s = (idx & 3) ^ ((r >> 1) & 3);
        gA[c] = g.X  + (size_t)(row0 + r) * 256 + s * 8;
        gB[c] = g.WT + (size_t)(col0 + r) * 256 + s * 8;
        lA[c] = As + w * 128 + c * 64;
        lB[c] = Bs + w * 128 + c * 64;
    }

    f32x4 acc[4][4] = {};
#pragma unroll
    for (int kk = 0; kk < 8; ++kk) {
        if (kk) __syncthreads();
        GLD16(gA[0] + kk * 32, lA[0]);
        GLD16(gB[0] + kk * 32, lB[0]);
        GLD16(gA[1] + kk * 32, lA[1]);
        GLD16(gB[1] + kk * 32, lB[1]);
        __syncthreads();
        B16 af[4], bfr[4];
#pragma unroll
        for (int i = 0; i < 4; ++i) {
            const int ra = wm * 64 + i * 16 + lr;
            af[i].u = As[ra * 4 + (ks4 ^ ((ra >> 1) & 3))];
            const int rb = wn * 64 + i * 16 + lr;
            bfr[i].u = Bs[rb * 4 + (ks4 ^ ((rb >> 1) & 3))];
        }
#pragma unroll
        for (int i = 0; i < 4; ++i)
#pragma unroll
            for (int jn = 0; jn < 4; ++jn)
                acc[i][jn] = __builtin_amdgcn_mfma_f32_16x16x32_bf16(af[i].s, bfr[jn].s, acc[i][jn], 0, 0, 0);
    }

    if (OUT_BF16) {
        const int er = l >> 2, ec = (l & 3) * 8;
#pragma unroll
        for (int i = 0; i < 4; ++i) {
            __syncthreads();
#pragma unroll
            for (int jn = 0; jn < 4; ++jn) {
                const float bv = g.bias[col0 + wn * 64 + jn * 16 + lr];
#pragma unroll
                for (int r = 0; r < 4; ++r) {
                    union { ushort u; __bf16 b; } cv;
                    cv.b = (__bf16)(acc[i][jn][r] + bv);
                    epi[w][ks4 * 4 + r][jn * 16 + lr] = cv.u;
                }
            }
            __syncthreads();
            const int grow = row0 + wm * 64 + i * 16 + er;
            if (grow < M) {
                uint4 v0 = *(const uint4*)&epi[w][er][ec];
                uint4 v1 = *(const uint4*)&epi[w][er][ec + 32];
                bf16_t* yp = (bf16_t*)g.Y + (size_t)grow * ldY + col0 + wn * 64;
                *(uint4*)(yp + ec) = v0;
                *(uint4*)(yp + ec + 32) = v1;
            }
        }
    } else {
        const int lq = l >> 4;
#pragma unroll
        for (int i = 0; i < 4; ++i) {
            const int rbase = row0 + wm * 64 + i * 16 + lq * 4;
#pragma unroll
            for (int jn = 0; jn < 4; ++jn) {
                const int col = col0 + wn * 64 + jn * 16 + lr;
                const float bv = g.bias[col];
#pragma unroll
                for (int r = 0; r < 4; ++r) {
                    const int grow = rbase + r;
                    if (grow < M) ((float*)g.Y)[(size_t)grow * ldY + col] = acc[i][jn][r] + bv;
                }
            }
        }
    }
}

// ---------- per-node online-softmax aggregation ----------
__device__ __forceinline__ float4 ldb4(const bf16_t* p) {
    bf16x4 v = *(const bf16x4*)p;
    return make_float4((float)v[0], (float)v[1], (float)v[2], (float)v[3]);
}

__device__ __forceinline__ void upd(float& m, float& den, float4& acc,
                                    float score, const float4& v) {
    const float nm = fmaxf(m, score);
    const float r = __expf(m - nm);
    const float p = __expf(score - nm);
    den = den * r + p;
    acc.x = acc.x * r + v.x * p;
    acc.y = acc.y * r + v.y * p;
    acc.z = acc.z * r + v.z * p;
    acc.w = acc.w * r + v.w * p;
    m = nm;
}

// single-list with 2-way unroll (authors)
__device__ __forceinline__ void aggr_list(
    const bf16_t* __restrict__ K, const bf16_t* __restrict__ V, int ld,
    const int* __restrict__ rp, const int* __restrict__ srcs,
    float scaleH, int node, int lane, const float4& q, float4& accOut)
{
    const int rs = rp[node], re = rp[node + 1];
    if (rs == re) return;
    float m = NEG_INF, den = 0.f;
    float4 acc = make_float4(0.f, 0.f, 0.f, 0.f);
    int i = rs;
    for (; i + 2 <= re; i += 2) {
        const int s0 = srcs[i], s1 = srcs[i + 1];
        const float4 k0 = ldb4(K + (size_t)s0 * ld + lane * 4);
        const float4 v0 = ldb4(V + (size_t)s0 * ld + lane * 4);
        const float4 k1 = ldb4(K + (size_t)s1 * ld + lane * 4);
        const float4 v1 = ldb4(V + (size_t)s1 * ld + lane * 4);
        float d0 = q.x * k0.x + q.y * k0.y + q.z * k0.z + q.w * k0.w;
        float d1 = q.x * k1.x + q.y * k1.y + q.z * k1.z + q.w * k1.w;
        d0 += __shfl_xor(d0, 1, 64); d1 += __shfl_xor(d1, 1, 64);
        d0 += __shfl_xor(d0, 2, 64); d1 += __shfl_xor(d1, 2, 64);
        d0 += __shfl_xor(d0, 4, 64); d1 += __shfl_xor(d1, 4, 64);
        const float sc0 = d0 * scaleH, sc1 = d1 * scaleH;
        const float nm = fmaxf(m, fmaxf(sc0, sc1));
        const float r  = __expf(m - nm);
        const float p0 = __expf(sc0 - nm);
        const float p1 = __expf(sc1 - nm);
        den = den * r + p0 + p1;
        acc.x = acc.x * r + v0.x * p0 + v1.x * p1;
        acc.y = acc.y * r + v0.y * p0 + v1.y * p1;
        acc.z = acc.z * r + v0.z * p0 + v1.z * p1;
        acc.w = acc.w * r + v0.w * p0 + v1.w * p1;
        m = nm;
    }
    if (i < re) {
        const int s0 = srcs[i];
        const float4 k0 = ldb4(K + (size_t)s0 * ld + lane * 4);
        const float4 v0 = ldb4(V + (size_t)s0 * ld + lane * 4);
        float d0 = q.x * k0.x + q.y * k0.y + q.z * k0.z + q.w * k0.w;
        d0 += __shfl_xor(d0, 1, 64);
        d0 += __shfl_xor(d0, 2, 64);
        d0 += __shfl_xor(d0, 4, 64);
        upd(m, den, acc, d0 * scaleH, v0);
    }
    const float inv = 1.f / den;
    accOut.x += acc.x * inv;
    accOut.y += acc.y * inv;
    accOut.z += acc.z * inv;
    accOut.w += acc.w * inv;
}

// dual-list lock-step (papers): two independent softmax chains, 4 gathers in flight
__device__ __forceinline__ void aggr_dual(
    const bf16_t* __restrict__ KA, const bf16_t* __restrict__ VA, int ldA,
    const int* __restrict__ rpA, const int* __restrict__ srA, float scA,
    const bf16_t* __restrict__ KB, const bf16_t* __restrict__ VB, int ldB,
    const int* __restrict__ rpB, const int* __restrict__ srB, float scB,
    int node, int lane, const float4& q, float4& accOut)
{
    int ai = rpA[node]; const int ae = rpA[node + 1];
    int bi = rpB[node]; const int be = rpB[node + 1];
    const bool hasA = ai < ae, hasB = bi < be;
    float mA = NEG_INF, dA = 0.f, mB = NEG_INF, dB = 0.f;
    float4 aA = make_float4(0.f, 0.f, 0.f, 0.f);
    float4 aB = make_float4(0.f, 0.f, 0.f, 0.f);
    while (ai < ae && bi < be) {
        const int sa = srA[ai], sb = srB[bi];
        const float4 ka = ldb4(KA + (size_t)sa * ldA + lane * 4);
        const float4 va = ldb4(VA + (size_t)sa * ldA + lane * 4);
        const float4 kb = ldb4(KB + (size_t)sb * ldB + lane * 4);
        const float4 vb = ldb4(VB + (size_t)sb * ldB + lane * 4);
        float da = q.x * ka.x + q.y * ka.y + q.z * ka.z + q.w * ka.w;
        float db = q.x * kb.x + q.y * kb.y + q.z * kb.z + q.w * kb.w;
        da += __shfl_xor(da, 1, 64); db += __shfl_xor(db, 1, 64);
        da += __shfl_xor(da, 2, 64); db += __shfl_xor(db, 2, 64);
        da += __shfl_xor(da, 4, 64); db += __shfl_xor(db, 4, 64);
        upd(mA, dA, aA, da * scA, va);
        upd(mB, dB, aB, db * scB, vb);
        ++ai; ++bi;
    }
    for (; ai < ae; ++ai) {
        const int sa = srA[ai];
        const float4 ka = ldb4(KA + (size_t)sa * ldA + lane * 4);
        const float4 va = ldb4(VA + (size_t)sa * ldA + lane * 4);
        float da = q.x * ka.x + q.y * ka.y + q.z * ka.z + q.w * ka.w;
        da += __shfl_xor(da, 1, 64);
        da += __shfl_xor(da, 2, 64);
        da += __shfl_xor(da, 4, 64);
        upd(mA, dA, aA, da * scA, va);
    }
    for (; bi < be; ++bi) {
        const int sb = srB[bi];
        const float4 kb = ldb4(KB + (size_t)sb * ldB + lane * 4);
        const float4 vb = ldb4(VB + (size_t)sb * ldB + lane * 4);
        float db = q.x * kb.x + q.y * kb.y + q.z * kb.z + q.w * kb.w;
        db += __shfl_xor(db, 1, 64);
        db += __shfl_xor(db, 2, 64);
        db += __shfl_xor(db, 4, 64);
        upd(mB, dB, aB, db * scB, vb);
    }
    if (hasA) {
        const float inv = 1.f / dA;
        accOut.x += aA.x * inv; accOut.y += aA.y * inv;
        accOut.z += aA.z * inv; accOut.w += aA.w * inv;
    }
    if (hasB) {
        const float inv = 1.f / dB;
        accOut.x += aB.x * inv; accOut.y += aB.y * inv;
        accOut.z += aB.z * inv; accOut.w += aB.w * inv;
    }
}

__global__ __launch_bounds__(256) void node_aggr(
    const bf16_t* __restrict__ Qp, const bf16_t* __restrict__ Qa,
    const bf16_t* __restrict__ Yhp, const bf16_t* __restrict__ Yha,
    const int* __restrict__ rp0, const int* __restrict__ sr0,
    const int* __restrict__ rp1, const int* __restrict__ sr1,
    const int* __restrict__ rp2, const int* __restrict__ sr2,
    const float* __restrict__ rel_pri, bf16_t* __restrict__ MUb)
{
    int gid = blockIdx.x * 256 + threadIdx.x;
    int node = gid >> 6;
    if (node >= NP + NA) return;
    int lane = gid & 63;
    int h = lane >> 3;
    float4 acc = make_float4(0.f, 0.f, 0.f, 0.f);
    float scale;
    if (node < NP) {
        const float4 q = ldb4(Qp + (size_t)node * 256 + lane * 4);
        aggr_dual(Yha, Yha + 256, 512,  rp0, sr0, rel_pri[h]     * INV_SQRT_DK,
                  Yhp, Yhp + 256, 1024, rp1, sr1, rel_pri[8 + h] * INV_SQRT_DK,
                  node, lane, q, acc);
        scale = 0.5f;
    } else {
        const int n2 = node - NP;
        const float4 q = ldb4(Qa + (size_t)n2 * 256 + lane * 4);
        aggr_list(Yhp + 512, Yhp + 768, 1024, rp2, sr2, rel_pri[16 + h] * INV_SQRT_DK, n2, lane, q, acc);
        scale = 1.f;
    }
    bf16x4 o;
    o[0] = (__bf16)(acc.x * scale); o[1] = (__bf16)(acc.y * scale);
    o[2] = (__bf16)(acc.z * scale); o[3] = (__bf16)(acc.w * scale);
    *(bf16x4*)(MUb + (size_t)node * 256 + lane * 4) = o;
}

// ---------- skip-blend + LayerNorm (merged node types, in-place on d_out) ----------
__global__ __launch_bounds__(256) void out_ln(
    const float* __restrict__ O, const float* __restrict__ Tp, const float* __restrict__ Ta,
    const float* __restrict__ skip, const float* __restrict__ lns,
    const float* __restrict__ lnb, float* __restrict__ out)
{
    int gid = blockIdx.x * 256 + threadIdx.x;
    int row = gid >> 6;
    if (row >= NP + NA) return;
    int lane = gid & 63;
    const int nt = row < NP ? 0 : 1;
    const float* T = (nt == 0) ? (Tp + (size_t)row * 256) : (Ta + (size_t)(row - NP) * 256);
    float alpha = 1.f / (1.f + expf(-skip[nt]));
    float beta = 1.f - alpha;
    const float4 o4 = *(const float4*)(O + (size_t)row * 256 + lane * 4);
    const float4 t4 = *(const float4*)(T + lane * 4);
    float v[4] = { o4.x * alpha + t4.x * beta, o4.y * alpha + t4.y * beta,
                   o4.z * alpha + t4.z * beta, o4.w * alpha + t4.w * beta };
    float s = v[0] + v[1] + v[2] + v[3];
#pragma unroll
    for (int mlane = 32; mlane >= 1; mlane >>= 1) s += __shfl_xor(s, mlane, 64);
    float mean = s * (1.f / 256.f);
    float sq = 0.f;
#pragma unroll
    for (int j = 0; j < 4; ++j) { float dd = v[j] - mean; sq += dd * dd; }
#pragma unroll
    for (int mlane = 32; mlane >= 1; mlane >>= 1) sq += __shfl_xor(sq, mlane, 64);
    float rstd = rsqrtf(sq * (1.f / 256.f) + 1e-5f);
    int c = lane * 4;
    const float* ls = lns + nt * 256 + c;
    const float* lb = lnb + nt * 256 + c;
    float4 r;
    r.x = (v[0] - mean) * rstd * ls[0] + lb[0];
    r.y = (v[1] - mean) * rstd * ls[1] + lb[1];
    r.z = (v[2] - mean) * rstd * ls[2] + lb[2];
    r.w = (v[3] - mean) * rstd * ls[3] + lb[3];
    *(float4*)(out + (size_t)row * 256 + c) = r;
}

extern "C" void kernel_launch(void* const* d_in, const int* in_sizes, int n_in,
                              void* d_out, int out_size, void* d_ws, size_t ws_size,
                              hipStream_t stream) {
    const float* h_paper  = (const float*)d_in[0];
    const float* h_author = (const float*)d_in[1];
    const float* t_paper  = (const float*)d_in[2];
    const float* t_author = (const float*)d_in[3];
    const float* k_w = (const float*)d_in[4];
    const float* k_b = (const float*)d_in[5];
    const float* q_w = (const float*)d_in[6];
    const float* q_b = (const float*)d_in[7];
    const float* v_w = (const float*)d_in[8];
    const float* v_b = (const float*)d_in[9];
    const float* a_w = (const float*)d_in[10];
    const float* a_b = (const float*)d_in[11];
    const float* rel_pri = (const float*)d_in[12];
    const float* rel_att = (const float*)d_in[13];
    const float* rel_msg = (const float*)d_in[14];
    const float* skip = (const float*)d_in[15];
    const float* ln_s = (const float*)d_in[16];
    const float* ln_b = (const float*)d_in[17];
    const int* src0 = (const int*)d_in[18];
    const int* dst0 = (const int*)d_in[19];
    const int* src1 = (const int*)d_in[20];
    const int* dst1 = (const int*)d_in[21];
    const int* src2 = (const int*)d_in[22];
    const int* dst2 = (const int*)d_in[23];

    const int NPpad = 20096, NApad = 10112;

    // ---- workspace layout ----
    char* base = (char*)d_ws;
    size_t off = 0;
    auto alloc = [&](size_t bytes) { char* p = base + off; off += (bytes + 255) & ~(size_t)255; return p; };
    bf16_t* Xhp  = (bf16_t*)alloc((size_t)NPpad * 256 * 2);
    bf16_t* Xha  = (bf16_t*)alloc((size_t)NApad * 256 * 2);
    bf16_t* Xtp  = (bf16_t*)alloc((size_t)NPpad * 256 * 2);
    bf16_t* Xta  = (bf16_t*)alloc((size_t)NApad * 256 * 2);
    bf16_t* Yhp  = (bf16_t*)alloc((size_t)NP * 1024 * 2);  // K1|V1|K2|V2
    bf16_t* Yha  = (bf16_t*)alloc((size_t)NA * 512 * 2);   // K0|V0
    bf16_t* Qp   = (bf16_t*)alloc((size_t)NP * 256 * 2);
    bf16_t* Qa   = (bf16_t*)alloc((size_t)NA * 256 * 2);
    bf16_t* MUb  = (bf16_t*)alloc((size_t)(NP + NApad) * 256 * 2);
    bf16_t* WT_hp = (bf16_t*)alloc(1024 * 256 * 2);
    bf16_t* WT_ha = (bf16_t*)alloc(512 * 256 * 2);
    bf16_t* WT_q0 = (bf16_t*)alloc(256 * 256 * 2);
    bf16_t* WT_q1 = (bf16_t*)alloc(256 * 256 * 2);
    bf16_t* WT_a0 = (bf16_t*)alloc(256 * 256 * 2);
    bf16_t* WT_a1 = (bf16_t*)alloc(256 * 256 * 2);
    float* Bhp = (float*)alloc(1024 * 4);
    float* Bha = (float*)alloc(512 * 4);
    int* cnt0 = (int*)alloc(100000 * 4);  // cnt0,cnt1,cnt2,run0,run1,run2 contiguous
    int* cnt1 = cnt0 + 20000;
    int* cnt2 = cnt1 + 20000;
    int* run0 = cnt2 + 10000;
    int* run1 = run0 + 20000;
    int* run2 = run1 + 20000;
    int* rp0 = (int*)alloc(20001 * 4);
    int* rp1 = (int*)alloc(20001 * 4);
    int* rp2 = (int*)alloc(10001 * 4);
    int* sr0 = (int*)alloc(100000 * 4);
    int* sr1 = (int*)alloc(100000 * 4);
    int* sr2 = (int*)alloc(100000 * 4);

    const int gE = (NEDGE + 255) / 256;

    // ---- weight prep + cnt zeroing (one launch, must precede count3) ----
    prep_weights<<<dim3(256, 11), 256, 0, stream>>>(k_w, k_b, v_w, v_b, q_w, a_w,
                                                    rel_att, rel_msg,
                                                    WT_hp, Bhp, WT_ha, Bha,
                                                    WT_q0, WT_q1, WT_a0, WT_a1, cnt0);

    // ---- CSR build ----
    count3<<<dim3(gE, 3), 256, 0, stream>>>(dst0, dst1, dst2, cnt0, cnt1, cnt2, NEDGE);
    scan3<<<3, 256, 0, stream>>>(cnt0, cnt1, cnt2, rp0, rp1, rp2);
    scatter3<<<dim3(gE, 3), 256, 0, stream>>>(src0, dst0, src1, dst1, src2, dst2,
                                              rp0, rp1, rp2, run0, run1, run2,
                                              sr0, sr1, sr2, NEDGE);

    // ---- X fp32 -> bf16 (one launch, 4 tensors) ----
    f2b4<<<dim3(2500, 4), 256, 0, stream>>>(h_paper,  Xhp, NP * 32,
                                            h_author, Xha, NA * 32,
                                            t_paper,  Xtp, NP * 32,
                                            t_author, Xta, NA * 32);

    // ---- all projections in ONE dispatch (bf16 in/out), 4 segments ----
    GSegs P{};
    P.s[0] = { Xhp, WT_hp, Bhp,       Yhp, NP, 8, 1024, 0 };
    P.s[1] = { Xha, WT_ha, Bha,       Yha, NA, 4, 512,  1256 };
    P.s[2] = { Xtp, WT_q0, q_b,       Qp,  NP, 2, 256,  1572 };
    P.s[3] = { Xta, WT_q1, q_b + 256, Qa,  NA, 2, 256,  1886 };
    P.n = 4;
    gemm_seg<1><<<2044, 256, 0, stream>>>(P);

    // ---- per-node online softmax + aggregation (bf16 out, 0.5 folded for papers) ----
    node_aggr<<<((NP + NA) * 64 + 255) / 256, 256, 0, stream>>>(
        Qp, Qa, Yhp, Yha, rp0, sr0, rp1, sr1, rp2, sr2, rel_pri, MUb);

    // ---- output linear (bf16 in, fp32 out), 2 segments ----
    float* out = (float*)d_out;
    GSegs O{};
    O.s[0] = { MUb,                    WT_a0, a_b,       out,                    NP, 2, 256, 0 };
    O.s[1] = { MUb + (size_t)NP * 256, WT_a1, a_b + 256, out + (size_t)NP * 256, NA, 2, 256, 314 };
    O.n = 2;
    gemm_seg<0><<<472, 256, 0, stream>>>(O);

    // ---- skip + LayerNorm (in-place) ----
    out_ln<<<((NP + NA) * 64 + 255) / 256, 256, 0, stream>>>(out, t_paper, t_author,
                                                             skip, ln_s, ln_b, out);
}